// Round 5
// baseline (12036.605 us; speedup 1.0000x reference)
//
#include <hip/hip_runtime.h>
#include <math.h>

#define NPTS 8192
#define NB 2
#define KNN 20
#define ROWS (NB*NPTS)   // 16384

// Reference-replication rules (np/XLA fp32):
//   inner[n,m] = sequential-c FMA chain (first term = rounded mul)
//   sq[n]      = sequential-c adds of ROUNDED squares (no FMA)
//   key        = (2.0f*inner - sq_n) - sq_m, all fp32
//   top-20     = stable (value desc, index asc)

__device__ __forceinline__ unsigned long long shfl_xor_u64(unsigned long long v, int m) {
  unsigned lo = (unsigned)__shfl_xor((int)(unsigned)(v & 0xFFFFFFFFull), m, 64);
  unsigned hi = (unsigned)__shfl_xor((int)(unsigned)(v >> 32), m, 64);
  return ((unsigned long long)hi << 32) | (unsigned long long)lo;
}

// map neg_d (fp32) to u64 so ascending u64 == (neg_d descending, idx ascending)
__device__ __forceinline__ unsigned long long packkey(float negd, int m) {
  unsigned nb = __float_as_uint(negd) ^ 0x80000000u;            // exact negation
  nb = (nb & 0x80000000u) ? ~nb : (nb | 0x80000000u);           // monotone asc map
  return ((unsigned long long)nb << 32) | (unsigned)m;
}

// ---------------- prep ----------------

// conv_w0 (64x6) -> Wt0[c][o] (c<6)
__global__ void prep_w0_kernel(const float* __restrict__ cw0, float* __restrict__ Wt0) {
  const int tid = threadIdx.x;                 // 384 threads
  const int c = tid >> 6, o = tid & 63;
  if (tid < 384) Wt0[c*64 + o] = cw0[o*6 + c];
}

// conv_ws (3x64x128) -> Wt[i][128][64]
__global__ void prep_wc_kernel(const float* __restrict__ cws, float* __restrict__ Wt) {
  const int f = blockIdx.x*256 + threadIdx.x;  // < 3*8192
  const int i = f >> 13, r = f & 8191, c = r >> 6, o = r & 63;
  Wt[f] = cws[i*8192 + o*128 + c];
}

// fuse_ws (3x64x128) -> fwt[i][128][64]
__global__ void prep_fw_kernel(const float* __restrict__ fws, float* __restrict__ fwt) {
  const int f = blockIdx.x*256 + threadIdx.x;  // < 3*8192
  const int i = f >> 13, r = f & 8191, c = r >> 6, o = r & 63;
  fwt[f] = fws[i*8192 + o*128 + c];
}

// x (B,3,N) -> xt[row]=float4(x0,x1,x2,0), xnorm[row] = seq sum of rounded squares
__global__ void prep_x_kernel(const float* __restrict__ x,
                              float* __restrict__ xt, float* __restrict__ xnorm) {
#pragma clang fp contract(off)
  const int t = blockIdx.x*256 + threadIdx.x;  // < ROWS
  const int b = t >> 13, n = t & (NPTS-1);
  const float v0 = x[((size_t)b*3 + 0)*NPTS + n];
  const float v1 = x[((size_t)b*3 + 1)*NPTS + n];
  const float v2 = x[((size_t)b*3 + 2)*NPTS + n];
  ((float4*)xt)[t] = make_float4(v0, v1, v2, 0.f);
  float a = __fmul_rn(v0, v0);
  a = __fadd_rn(a, __fmul_rn(v1, v1));
  a = __fadd_rn(a, __fmul_rn(v2, v2));
  xnorm[t] = a;
}

// ---------------- KNN (np-faithful fp32 keys: seq-FMA inner; stable top-20) ----------------

__global__ __launch_bounds__(256)
void knn0_kernel(const float* __restrict__ pts, const float* __restrict__ norms,
                 int* __restrict__ idx) {
#pragma clang fp contract(off)
  const int tid = threadIdx.x;
  const int wave = tid >> 6, lane = tid & 63;
  const int row = blockIdx.x*4 + wave;
  const int b = row >> 13, n = row & (NPTS-1);
  const float4* P = ((const float4*)pts) + (size_t)b * NPTS;
  const float4 rv = P[n];
  const float* nrm = norms + (size_t)b*NPTS;
  const float nrmN = nrm[n];

  unsigned long long keys[12];
#pragma unroll
  for (int i = 0; i < 12; ++i) keys[i] = ~0ull;

  for (int t = 0; t < NPTS/64; ++t) {
    const int m = t*64 + lane;
    const float4 q = P[m];
    float acc = __fmul_rn(rv.x, q.x);      // fma(a0,b0,0) == rounded mul
    acc = fmaf(rv.y, q.y, acc);
    acc = fmaf(rv.z, q.z, acc);
    const float negd = __fsub_rn(__fsub_rn(__fmul_rn(2.0f, acc), nrmN), nrm[m]);
    unsigned long long uk = packkey(negd, m);
    if (uk < keys[11]) {
#pragma unroll
      for (int i = 0; i < 12; ++i)
        if (uk < keys[i]) { const unsigned long long tmp = keys[i]; keys[i] = uk; uk = tmp; }
    }
  }

  int stash = 0;
  unsigned long long head = keys[0];
  for (int r = 0; r < KNN; ++r) {
    unsigned long long best = head;
#pragma unroll
    for (int off = 32; off; off >>= 1) {
      const unsigned long long o = shfl_xor_u64(best, off);
      if (o < best) best = o;
    }
    if (head == best) {
#pragma unroll
      for (int i = 0; i < 11; ++i) keys[i] = keys[i+1];
      keys[11] = ~0ull;
      head = keys[0];
    }
    if (lane == r) stash = (int)(unsigned)(best & 0xFFFFFFFFull);
  }
  if (lane < KNN) idx[(size_t)row*KNN + lane] = stash;
}

__global__ __launch_bounds__(256)
void knn64_kernel(const float* __restrict__ hf, const float* __restrict__ norms,
                  int* __restrict__ idx) {
#pragma clang fp contract(off)
  const int tid = threadIdx.x;
  const int wave = tid >> 6, lane = tid & 63;
  const int row = blockIdx.x*4 + wave;
  const int b = row >> 13, n = row & (NPTS-1);
  const float4* P = ((const float4*)hf) + (size_t)b * NPTS * 16;
  float4 rv[16];
#pragma unroll
  for (int i = 0; i < 16; ++i) rv[i] = P[(size_t)n*16 + i];
  const float* nrm = norms + (size_t)b*NPTS;
  const float nrmN = nrm[n];

  unsigned long long keys[12];
#pragma unroll
  for (int i = 0; i < 12; ++i) keys[i] = ~0ull;

  for (int t = 0; t < NPTS/64; ++t) {
    const int m = t*64 + lane;
    const float4* Q = P + (size_t)m*16;
    // sequential-c FMA chain, c ascending (np SIMD einsum / sgemm order)
    float acc;
#pragma unroll
    for (int i = 0; i < 16; ++i) {
      const float4 q = Q[i];
      if (i == 0) acc = __fmul_rn(rv[0].x, q.x);
      else        acc = fmaf(rv[i].x, q.x, acc);
      acc = fmaf(rv[i].y, q.y, acc);
      acc = fmaf(rv[i].z, q.z, acc);
      acc = fmaf(rv[i].w, q.w, acc);
    }
    const float negd = __fsub_rn(__fsub_rn(__fmul_rn(2.0f, acc), nrmN), nrm[m]);
    unsigned long long uk = packkey(negd, m);
    if (uk < keys[11]) {
#pragma unroll
      for (int i = 0; i < 12; ++i)
        if (uk < keys[i]) { const unsigned long long tmp = keys[i]; keys[i] = uk; uk = tmp; }
    }
  }

  int stash = 0;
  unsigned long long head = keys[0];
  for (int r = 0; r < KNN; ++r) {
    unsigned long long best = head;
#pragma unroll
    for (int off = 32; off; off >>= 1) {
      const unsigned long long o = shfl_xor_u64(best, off);
      if (o < best) best = o;
    }
    if (head == best) {
#pragma unroll
      for (int i = 0; i < 11; ++i) keys[i] = keys[i+1];
      keys[11] = ~0ull;
      head = keys[0];
    }
    if (lane == r) stash = (int)(unsigned)(best & 0xFFFFFFFFull);
  }
  if (lane < KNN) idx[(size_t)row*KNN + lane] = stash;
}

// ---------------- conv layer 0: literal per-neighbor conv, BN, lrelu, max ----------------
__global__ __launch_bounds__(256)
void conv0_kernel(const int* __restrict__ idx, const float* __restrict__ xt,
                  const float* __restrict__ Wt0, const float* __restrict__ gam,
                  const float* __restrict__ bet, const float* __restrict__ rmn,
                  const float* __restrict__ rvr,
                  float* __restrict__ outc, float* __restrict__ hpm) {
#pragma clang fp contract(off)
  const int tid = threadIdx.x, wave = tid >> 6, lane = tid & 63;
  const int row = blockIdx.x*4 + wave;
  const int b = row >> 13, n = row & (NPTS-1);
  const float4* P = ((const float4*)xt) + (size_t)b * NPTS;
  const float4 ctr = P[n];
  float wv[6];
#pragma unroll
  for (int c = 0; c < 6; ++c) wv[c] = Wt0[c*64 + lane];
  const float sc = __fdiv_rn(gam[lane], sqrtf(__fadd_rn(rvr[lane], 1e-5f)));
  const float mn = rmn[lane], bt = bet[lane];

  float mx = -3.0e38f;
  const int* ip = idx + (size_t)row*KNN;
  for (int k = 0; k < KNN; ++k) {
    const float4 q = P[ip[k]];
    float acc = __fmul_rn(wv[0], __fsub_rn(q.x, ctr.x));
    acc = __fadd_rn(acc, __fmul_rn(wv[1], __fsub_rn(q.y, ctr.y)));
    acc = __fadd_rn(acc, __fmul_rn(wv[2], __fsub_rn(q.z, ctr.z)));
    acc = __fadd_rn(acc, __fmul_rn(wv[3], ctr.x));
    acc = __fadd_rn(acc, __fmul_rn(wv[4], ctr.y));
    acc = __fadd_rn(acc, __fmul_rn(wv[5], ctr.z));
    float y = __fadd_rn(__fmul_rn(__fsub_rn(acc, mn), sc), bt);
    y = (y >= 0.f) ? y : __fmul_rn(0.2f, y);
    mx = fmaxf(mx, y);
  }
  outc[((size_t)(b*64 + lane))*NPTS + n] = mx;
  hpm[(size_t)row*64 + lane] = mx;
}

// ---------------- conv layers 1-3: literal per-neighbor conv (128-ch), BN, lrelu, max ----------------
__global__ __launch_bounds__(256)
void convL_kernel(const int* __restrict__ idx, const float* __restrict__ hf,
                  const float* __restrict__ WtL, const float* __restrict__ gam,
                  const float* __restrict__ bet, const float* __restrict__ rmn,
                  const float* __restrict__ rvr, const int L,
                  float* __restrict__ outc, float* __restrict__ hpm) {
#pragma clang fp contract(off)
  __shared__ float ls[21*64];          // row 0 = ctr, rows 1..20 = neighbors
  __shared__ float pmax[4*64];
  const int tid = threadIdx.x, wave = tid >> 6, lane = tid & 63;
  const int row = blockIdx.x;
  const int b = row >> 13, n = row & (NPTS-1);
  const int* ip = idx + (size_t)row*KNN;
#pragma unroll
  for (int j = 0; j < 6; ++j) {
    const int r = j*4 + wave;
    if (r < 21) {
      const int src = (r == 0) ? row : (b*NPTS + ip[r-1]);
      ls[r*64 + lane] = hf[(size_t)src*64 + lane];
    }
  }
  __syncthreads();

  float wv[128];
#pragma unroll
  for (int c = 0; c < 128; ++c) wv[c] = WtL[c*64 + lane];
  const float sc = __fdiv_rn(gam[L*64 + lane], sqrtf(__fadd_rn(rvr[L*64 + lane], 1e-5f)));
  const float mn = rmn[L*64 + lane], bt = bet[L*64 + lane];

  float mx = -3.0e38f;
  for (int j = 0; j < 5; ++j) {
    const int k = wave*5 + j;
    const float* nb = &ls[(1+k)*64];
    float acc = __fmul_rn(wv[0], __fsub_rn(nb[0], ls[0]));
#pragma unroll
    for (int c = 1; c < 64; ++c)
      acc = __fadd_rn(acc, __fmul_rn(wv[c], __fsub_rn(nb[c], ls[c])));
#pragma unroll
    for (int c = 64; c < 128; ++c)
      acc = __fadd_rn(acc, __fmul_rn(wv[c], ls[c-64]));
    float y = __fadd_rn(__fmul_rn(__fsub_rn(acc, mn), sc), bt);
    y = (y >= 0.f) ? y : __fmul_rn(0.2f, y);
    mx = fmaxf(mx, y);
  }
  pmax[wave*64 + lane] = mx;
  __syncthreads();
  if (tid < 64) {
    const float m01 = fmaxf(pmax[tid], pmax[64 + tid]);
    const float m23 = fmaxf(pmax[128 + tid], pmax[192 + tid]);
    const float m = fmaxf(m01, m23);
    outc[((size_t)(b*64 + tid))*NPTS + n] = m;
    hpm[(size_t)row*64 + tid] = m;
  }
}

// ---------------- fuse: hf = elu(fw . [h; reps]); + hnorm (seq sum of rounded squares) ----------------
__global__ __launch_bounds__(256)
void fuse_kernel(const float* __restrict__ hpm, const float* __restrict__ repsL,
                 const float* __restrict__ fwtL, float* __restrict__ hf,
                 float* __restrict__ hnorm) {
#pragma clang fp contract(off)
  __shared__ float cs[32*130];   // 32 points x 128 channels (+2 pad)
  __shared__ float yb[32*65];    // fused outputs for the sq pass
  const int tid = threadIdx.x, wave = tid >> 6, lane = tid & 63;
  const size_t rowbase = (size_t)blockIdx.x*32;          // b*N + n0
  const int b = (int)(rowbase >> 13);
  const int n0 = (int)(rowbase & (NPTS-1));
#pragma unroll
  for (int j = 0; j < 8; ++j) {
    const int p = j*4 + wave;
    cs[p*130 + lane] = hpm[(rowbase + p)*64 + lane];
  }
  const float* rb = repsL + (size_t)b*64*NPTS;
  const int pl = lane & 31;
#pragma unroll
  for (int j = 0; j < 8; ++j) {
    const int c = j*8 + wave*2 + (lane >> 5);
    cs[pl*130 + 64 + c] = rb[(size_t)c*NPTS + n0 + pl];
  }
  __syncthreads();
  float wv[128];
#pragma unroll
  for (int c = 0; c < 128; ++c) wv[c] = fwtL[c*64 + lane];
  for (int pp = 0; pp < 8; ++pp) {
    const int p = wave*8 + pp;
    float acc = __fmul_rn(wv[0], cs[p*130]);
#pragma unroll
    for (int c = 1; c < 128; ++c)
      acc = __fadd_rn(acc, __fmul_rn(wv[c], cs[p*130 + c]));
    const float y = (acc > 0.f) ? acc : (float)expm1((double)acc);  // jax.nn.elu
    hf[(rowbase + p)*64 + lane] = y;
    yb[p*65 + lane] = y;
  }
  __syncthreads();
  if (tid < 32) {
    float a = __fmul_rn(yb[tid*65], yb[tid*65]);
#pragma unroll
    for (int c = 1; c < 64; ++c) {
      const float t = yb[tid*65 + c];
      a = __fadd_rn(a, __fmul_rn(t, t));
    }
    hnorm[rowbase + tid] = a;
  }
}

// ---------------- launch ----------------
extern "C" void kernel_launch(void* const* d_in, const int* in_sizes, int n_in,
                              void* d_out, int out_size, void* d_ws, size_t ws_size,
                              hipStream_t stream) {
  const float* x    = (const float*)d_in[0];
  const float* reps = (const float*)d_in[1];
  const float* cw0  = (const float*)d_in[2];
  const float* cws  = (const float*)d_in[3];
  const float* gam  = (const float*)d_in[4];
  const float* bet  = (const float*)d_in[5];
  const float* rmn  = (const float*)d_in[6];
  const float* rvr  = (const float*)d_in[7];
  const float* fws  = (const float*)d_in[8];
  float* out = (float*)d_out;

  int* idx = (int*)d_ws;
  float* w = (float*)d_ws + (size_t)ROWS*KNN;
  float* xt    = w;  w += (size_t)ROWS*4;
  float* xnorm = w;  w += ROWS;
  float* hf    = w;  w += (size_t)ROWS*64;
  float* hnorm = w;  w += ROWS;
  float* hpm   = w;  w += (size_t)ROWS*64;
  float* Wt0   = w;  w += 8*64;
  float* Wt    = w;  w += 3*128*64;
  float* fwt   = w;  w += 3*128*64;

  hipLaunchKernelGGL(prep_w0_kernel, dim3(1),   dim3(384), 0, stream, cw0, Wt0);
  hipLaunchKernelGGL(prep_wc_kernel, dim3(96),  dim3(256), 0, stream, cws, Wt);
  hipLaunchKernelGGL(prep_fw_kernel, dim3(96),  dim3(256), 0, stream, fws, fwt);
  hipLaunchKernelGGL(prep_x_kernel,  dim3(ROWS/256), dim3(256), 0, stream, x, xt, xnorm);

  const size_t chunk = (size_t)NB*64*NPTS;

  // layer 0
  hipLaunchKernelGGL(knn0_kernel,  dim3(ROWS/4), dim3(256), 0, stream, xt, xnorm, idx);
  hipLaunchKernelGGL(conv0_kernel, dim3(ROWS/4), dim3(256), 0, stream,
                     idx, xt, Wt0, gam, bet, rmn, rvr, out, hpm);

  for (int i = 0; i < 3; ++i) {
    hipLaunchKernelGGL(fuse_kernel, dim3(ROWS/32), dim3(256), 0, stream,
                       hpm, reps + (size_t)i*NB*64*NPTS, fwt + (size_t)i*8192, hf, hnorm);
    hipLaunchKernelGGL(knn64_kernel, dim3(ROWS/4), dim3(256), 0, stream, hf, hnorm, idx);
    hipLaunchKernelGGL(convL_kernel, dim3(ROWS), dim3(256), 0, stream,
                       idx, hf, Wt + (size_t)i*8192, gam, bet, rmn, rvr, i + 1,
                       out + (size_t)(i+1)*chunk, hpm);
  }
}

// Round 6
// 4287.989 us; speedup vs baseline: 2.8071x; 2.8071x over previous
//
#include <hip/hip_runtime.h>
#include <math.h>

#define NPTS 8192
#define NB 2
#define KNN 20
#define ROWS (NB*NPTS)   // 16384
#define NSPLIT 16        // candidate-range splits per row (knn64)
#define CPS (NPTS/NSPLIT) // 512 candidates per scanner
#define KEEP 12          // exact top-KEEP per scanner; P(overflow) ~1e-11/row

// Reference-replication rules (np/XLA fp32):
//   inner[n,m] = sequential-c FMA chain (first term = rounded mul)
//   sq[n]      = sequential-c adds of ROUNDED squares (no FMA)
//   key        = (2.0f*inner - sq_n) - sq_m, all fp32
//   top-20     = stable (value desc, index asc)

__device__ __forceinline__ unsigned long long shfl_xor_u64(unsigned long long v, int m) {
  unsigned lo = (unsigned)__shfl_xor((int)(unsigned)(v & 0xFFFFFFFFull), m, 64);
  unsigned hi = (unsigned)__shfl_xor((int)(unsigned)(v >> 32), m, 64);
  return ((unsigned long long)hi << 32) | (unsigned long long)lo;
}

// map neg_d (fp32) to u64 so ascending u64 == (neg_d descending, idx ascending)
__device__ __forceinline__ unsigned long long packkey(float negd, int m) {
  unsigned nb = __float_as_uint(negd) ^ 0x80000000u;            // exact negation
  nb = (nb & 0x80000000u) ? ~nb : (nb | 0x80000000u);           // monotone asc map
  return ((unsigned long long)nb << 32) | (unsigned)m;
}

// ---------------- prep ----------------

__global__ void prep_w0_kernel(const float* __restrict__ cw0, float* __restrict__ Wt0) {
  const int tid = threadIdx.x;                 // 384 threads
  const int c = tid >> 6, o = tid & 63;
  if (tid < 384) Wt0[c*64 + o] = cw0[o*6 + c];
}

__global__ void prep_wc_kernel(const float* __restrict__ cws, float* __restrict__ Wt) {
  const int f = blockIdx.x*256 + threadIdx.x;  // < 3*8192
  const int i = f >> 13, r = f & 8191, c = r >> 6, o = r & 63;
  Wt[f] = cws[i*8192 + o*128 + c];
}

__global__ void prep_fw_kernel(const float* __restrict__ fws, float* __restrict__ fwt) {
  const int f = blockIdx.x*256 + threadIdx.x;  // < 3*8192
  const int i = f >> 13, r = f & 8191, c = r >> 6, o = r & 63;
  fwt[f] = fws[i*8192 + o*128 + c];
}

__global__ void prep_x_kernel(const float* __restrict__ x,
                              float* __restrict__ xt, float* __restrict__ xnorm) {
#pragma clang fp contract(off)
  const int t = blockIdx.x*256 + threadIdx.x;  // < ROWS
  const int b = t >> 13, n = t & (NPTS-1);
  const float v0 = x[((size_t)b*3 + 0)*NPTS + n];
  const float v1 = x[((size_t)b*3 + 1)*NPTS + n];
  const float v2 = x[((size_t)b*3 + 2)*NPTS + n];
  ((float4*)xt)[t] = make_float4(v0, v1, v2, 0.f);
  float a = __fmul_rn(v0, v0);
  a = __fadd_rn(a, __fmul_rn(v1, v1));
  a = __fadd_rn(a, __fmul_rn(v2, v2));
  xnorm[t] = a;
}

// ---------------- KNN layer 0 (wave-per-row; coalesced float4 stream) ----------------
__global__ __launch_bounds__(256)
void knn0_kernel(const float* __restrict__ pts, const float* __restrict__ norms,
                 int* __restrict__ idx) {
#pragma clang fp contract(off)
  const int tid = threadIdx.x;
  const int wave = tid >> 6, lane = tid & 63;
  const int row = blockIdx.x*4 + wave;
  const int b = row >> 13, n = row & (NPTS-1);
  const float4* P = ((const float4*)pts) + (size_t)b * NPTS;
  const float4 rv = P[n];
  const float* nrm = norms + (size_t)b*NPTS;
  const float nrmN = nrm[n];

  unsigned long long keys[12];
#pragma unroll
  for (int i = 0; i < 12; ++i) keys[i] = ~0ull;

  for (int t = 0; t < NPTS/64; ++t) {
    const int m = t*64 + lane;
    const float4 q = P[m];
    float acc = __fmul_rn(rv.x, q.x);      // fma(a0,b0,0) == rounded mul
    acc = fmaf(rv.y, q.y, acc);
    acc = fmaf(rv.z, q.z, acc);
    const float negd = __fsub_rn(__fsub_rn(__fmul_rn(2.0f, acc), nrmN), nrm[m]);
    unsigned long long uk = packkey(negd, m);
    if (uk < keys[11]) {
#pragma unroll
      for (int i = 0; i < 12; ++i)
        if (uk < keys[i]) { const unsigned long long tmp = keys[i]; keys[i] = uk; uk = tmp; }
    }
  }

  int stash = 0;
  unsigned long long head = keys[0];
  for (int r = 0; r < KNN; ++r) {
    unsigned long long best = head;
#pragma unroll
    for (int off = 32; off; off >>= 1) {
      const unsigned long long o = shfl_xor_u64(best, off);
      if (o < best) best = o;
    }
    if (head == best) {
#pragma unroll
      for (int i = 0; i < 11; ++i) keys[i] = keys[i+1];
      keys[11] = ~0ull;
      head = keys[0];
    }
    if (lane == r) stash = (int)(unsigned)(best & 0xFFFFFFFFull);
  }
  if (lane < KNN) idx[(size_t)row*KNN + lane] = stash;
}

// ---------------- KNN layers 1-3, pass 1: thread-per-row scan ----------------
// Candidate features are block-uniform (same range for all 256 rows in the
// block) -> compiler emits scalar (SGPR/K$) loads; FMA reads the SGPR operand
// directly. Exact sorted top-KEEP per (row, split) written to scratch.
__global__ __launch_bounds__(256)
void knn64_scan_kernel(const float* __restrict__ hf, const float* __restrict__ norms,
                       unsigned long long* __restrict__ cand) {
#pragma clang fp contract(off)
  const int tid = threadIdx.x;
  const int rb = blockIdx.x >> 4, cs = blockIdx.x & (NSPLIT-1);
  const int row = rb*256 + tid;          // 256 consecutive rows; batch-uniform
  const int b = row >> 13, n = row & (NPTS-1);

  float4 f[16];
  const float4* Pf = ((const float4*)hf) + (size_t)row*16;
#pragma unroll
  for (int i = 0; i < 16; ++i) f[i] = Pf[i];
  const float* nrm = norms + (size_t)b*NPTS;
  const float nrmN = nrm[n];

  const float* Pc = hf + ((size_t)b*NPTS + (size_t)cs*CPS)*64;   // uniform base
  const float* nrmC = nrm + cs*CPS;                               // uniform base

  unsigned long long keys[KEEP];
#pragma unroll
  for (int i = 0; i < KEEP; ++i) keys[i] = ~0ull;

  for (int j = 0; j < CPS; ++j) {
    const float* q = Pc + (size_t)j*64;   // wave-uniform address
    float acc = __fmul_rn(f[0].x, q[0]);
    acc = fmaf(f[0].y, q[1], acc);
    acc = fmaf(f[0].z, q[2], acc);
    acc = fmaf(f[0].w, q[3], acc);
#pragma unroll
    for (int i = 1; i < 16; ++i) {
      acc = fmaf(f[i].x, q[4*i+0], acc);
      acc = fmaf(f[i].y, q[4*i+1], acc);
      acc = fmaf(f[i].z, q[4*i+2], acc);
      acc = fmaf(f[i].w, q[4*i+3], acc);
    }
    const float negd = __fsub_rn(__fsub_rn(__fmul_rn(2.0f, acc), nrmN), nrmC[j]);
    unsigned long long uk = packkey(negd, cs*CPS + j);
    if (uk < keys[KEEP-1]) {
#pragma unroll
      for (int i = 0; i < KEEP; ++i)
        if (uk < keys[i]) { const unsigned long long tmp = keys[i]; keys[i] = uk; uk = tmp; }
    }
  }

  unsigned long long* o = cand + ((size_t)row*NSPLIT + cs)*KEEP;
#pragma unroll
  for (int i = 0; i < KEEP; ++i) o[i] = keys[i];   // ascending (sorted)
}

// ---------------- KNN layers 1-3, pass 2: wave-per-row merge of 192 keys ----------------
// Lane l holds flat keys [3l,3l+3) of the row's NSPLIT*KEEP=192; 12%3==0 so a
// lane never crosses a split boundary -> its 3 keys are already ascending.
__global__ __launch_bounds__(256)
void knn64_merge_kernel(const unsigned long long* __restrict__ cand,
                        int* __restrict__ idx) {
  const int tid = threadIdx.x, wave = tid >> 6, lane = tid & 63;
  const int row = blockIdx.x*4 + wave;
  const unsigned long long* cr = cand + (size_t)row*(NSPLIT*KEEP);
  unsigned long long a0 = cr[lane*3 + 0];
  unsigned long long a1 = cr[lane*3 + 1];
  unsigned long long a2 = cr[lane*3 + 2];

  int stash = 0;
  for (int r = 0; r < KNN; ++r) {
    unsigned long long best = a0;
#pragma unroll
    for (int off = 32; off; off >>= 1) {
      const unsigned long long o = shfl_xor_u64(best, off);
      if (o < best) best = o;
    }
    if (a0 == best) { a0 = a1; a1 = a2; a2 = ~0ull; }   // unique keys: one winner
    if (lane == r) stash = (int)(unsigned)(best & 0xFFFFFFFFull);
  }
  if (lane < KNN) idx[(size_t)row*KNN + lane] = stash;
}

// ---------------- conv layer 0: literal per-neighbor conv, BN, lrelu, max ----------------
__global__ __launch_bounds__(256)
void conv0_kernel(const int* __restrict__ idx, const float* __restrict__ xt,
                  const float* __restrict__ Wt0, const float* __restrict__ gam,
                  const float* __restrict__ bet, const float* __restrict__ rmn,
                  const float* __restrict__ rvr,
                  float* __restrict__ outc, float* __restrict__ hpm) {
#pragma clang fp contract(off)
  const int tid = threadIdx.x, wave = tid >> 6, lane = tid & 63;
  const int row = blockIdx.x*4 + wave;
  const int b = row >> 13, n = row & (NPTS-1);
  const float4* P = ((const float4*)xt) + (size_t)b * NPTS;
  const float4 ctr = P[n];
  float wv[6];
#pragma unroll
  for (int c = 0; c < 6; ++c) wv[c] = Wt0[c*64 + lane];
  const float sc = __fdiv_rn(gam[lane], sqrtf(__fadd_rn(rvr[lane], 1e-5f)));
  const float mn = rmn[lane], bt = bet[lane];

  float mx = -3.0e38f;
  const int* ip = idx + (size_t)row*KNN;
  for (int k = 0; k < KNN; ++k) {
    const float4 q = P[ip[k]];
    float acc = __fmul_rn(wv[0], __fsub_rn(q.x, ctr.x));
    acc = __fadd_rn(acc, __fmul_rn(wv[1], __fsub_rn(q.y, ctr.y)));
    acc = __fadd_rn(acc, __fmul_rn(wv[2], __fsub_rn(q.z, ctr.z)));
    acc = __fadd_rn(acc, __fmul_rn(wv[3], ctr.x));
    acc = __fadd_rn(acc, __fmul_rn(wv[4], ctr.y));
    acc = __fadd_rn(acc, __fmul_rn(wv[5], ctr.z));
    float y = __fadd_rn(__fmul_rn(__fsub_rn(acc, mn), sc), bt);
    y = (y >= 0.f) ? y : __fmul_rn(0.2f, y);
    mx = fmaxf(mx, y);
  }
  outc[((size_t)(b*64 + lane))*NPTS + n] = mx;
  hpm[(size_t)row*64 + lane] = mx;
}

// ---------------- conv layers 1-3: literal per-neighbor conv (128-ch), BN, lrelu, max ----------------
__global__ __launch_bounds__(256)
void convL_kernel(const int* __restrict__ idx, const float* __restrict__ hf,
                  const float* __restrict__ WtL, const float* __restrict__ gam,
                  const float* __restrict__ bet, const float* __restrict__ rmn,
                  const float* __restrict__ rvr, const int L,
                  float* __restrict__ outc, float* __restrict__ hpm) {
#pragma clang fp contract(off)
  __shared__ float ls[21*64];          // row 0 = ctr, rows 1..20 = neighbors
  __shared__ float pmax[4*64];
  const int tid = threadIdx.x, wave = tid >> 6, lane = tid & 63;
  const int row = blockIdx.x;
  const int b = row >> 13, n = row & (NPTS-1);
  const int* ip = idx + (size_t)row*KNN;
#pragma unroll
  for (int j = 0; j < 6; ++j) {
    const int r = j*4 + wave;
    if (r < 21) {
      const int src = (r == 0) ? row : (b*NPTS + ip[r-1]);
      ls[r*64 + lane] = hf[(size_t)src*64 + lane];
    }
  }
  __syncthreads();

  float wv[128];
#pragma unroll
  for (int c = 0; c < 128; ++c) wv[c] = WtL[c*64 + lane];
  const float sc = __fdiv_rn(gam[L*64 + lane], sqrtf(__fadd_rn(rvr[L*64 + lane], 1e-5f)));
  const float mn = rmn[L*64 + lane], bt = bet[L*64 + lane];

  float mx = -3.0e38f;
  for (int j = 0; j < 5; ++j) {
    const int k = wave*5 + j;
    const float* nb = &ls[(1+k)*64];
    float acc = __fmul_rn(wv[0], __fsub_rn(nb[0], ls[0]));
#pragma unroll
    for (int c = 1; c < 64; ++c)
      acc = __fadd_rn(acc, __fmul_rn(wv[c], __fsub_rn(nb[c], ls[c])));
#pragma unroll
    for (int c = 64; c < 128; ++c)
      acc = __fadd_rn(acc, __fmul_rn(wv[c], ls[c-64]));
    float y = __fadd_rn(__fmul_rn(__fsub_rn(acc, mn), sc), bt);
    y = (y >= 0.f) ? y : __fmul_rn(0.2f, y);
    mx = fmaxf(mx, y);
  }
  pmax[wave*64 + lane] = mx;
  __syncthreads();
  if (tid < 64) {
    const float m01 = fmaxf(pmax[tid], pmax[64 + tid]);
    const float m23 = fmaxf(pmax[128 + tid], pmax[192 + tid]);
    const float m = fmaxf(m01, m23);
    outc[((size_t)(b*64 + tid))*NPTS + n] = m;
    hpm[(size_t)row*64 + tid] = m;
  }
}

// ---------------- fuse: hf = elu(fw . [h; reps]); + hnorm (seq sum of rounded squares) ----------------
__global__ __launch_bounds__(256)
void fuse_kernel(const float* __restrict__ hpm, const float* __restrict__ repsL,
                 const float* __restrict__ fwtL, float* __restrict__ hf,
                 float* __restrict__ hnorm) {
#pragma clang fp contract(off)
  __shared__ float cs[32*130];   // 32 points x 128 channels (+2 pad)
  __shared__ float yb[32*65];    // fused outputs for the sq pass
  const int tid = threadIdx.x, wave = tid >> 6, lane = tid & 63;
  const size_t rowbase = (size_t)blockIdx.x*32;          // b*N + n0
  const int b = (int)(rowbase >> 13);
  const int n0 = (int)(rowbase & (NPTS-1));
#pragma unroll
  for (int j = 0; j < 8; ++j) {
    const int p = j*4 + wave;
    cs[p*130 + lane] = hpm[(rowbase + p)*64 + lane];
  }
  const float* rb = repsL + (size_t)b*64*NPTS;
  const int pl = lane & 31;
#pragma unroll
  for (int j = 0; j < 8; ++j) {
    const int c = j*8 + wave*2 + (lane >> 5);
    cs[pl*130 + 64 + c] = rb[(size_t)c*NPTS + n0 + pl];
  }
  __syncthreads();
  float wv[128];
#pragma unroll
  for (int c = 0; c < 128; ++c) wv[c] = fwtL[c*64 + lane];
  for (int pp = 0; pp < 8; ++pp) {
    const int p = wave*8 + pp;
    float acc = __fmul_rn(wv[0], cs[p*130]);
#pragma unroll
    for (int c = 1; c < 128; ++c)
      acc = __fadd_rn(acc, __fmul_rn(wv[c], cs[p*130 + c]));
    const float y = (acc > 0.f) ? acc : (float)expm1((double)acc);  // jax.nn.elu
    hf[(rowbase + p)*64 + lane] = y;
    yb[p*65 + lane] = y;
  }
  __syncthreads();
  if (tid < 32) {
    float a = __fmul_rn(yb[tid*65], yb[tid*65]);
#pragma unroll
    for (int c = 1; c < 64; ++c) {
      const float t = yb[tid*65 + c];
      a = __fadd_rn(a, __fmul_rn(t, t));
    }
    hnorm[rowbase + tid] = a;
  }
}

// ---------------- launch ----------------
extern "C" void kernel_launch(void* const* d_in, const int* in_sizes, int n_in,
                              void* d_out, int out_size, void* d_ws, size_t ws_size,
                              hipStream_t stream) {
  const float* x    = (const float*)d_in[0];
  const float* reps = (const float*)d_in[1];
  const float* cw0  = (const float*)d_in[2];
  const float* cws  = (const float*)d_in[3];
  const float* gam  = (const float*)d_in[4];
  const float* bet  = (const float*)d_in[5];
  const float* rmn  = (const float*)d_in[6];
  const float* rvr  = (const float*)d_in[7];
  const float* fws  = (const float*)d_in[8];
  float* out = (float*)d_out;

  unsigned long long* cand = (unsigned long long*)d_ws;        // ROWS*16*12 u64 = 25.2MB
  int* idx = (int*)(cand + (size_t)ROWS*NSPLIT*KEEP);
  float* w = (float*)(idx + (size_t)ROWS*KNN);
  float* xt    = w;  w += (size_t)ROWS*4;
  float* xnorm = w;  w += ROWS;
  float* hf    = w;  w += (size_t)ROWS*64;
  float* hnorm = w;  w += ROWS;
  float* hpm   = w;  w += (size_t)ROWS*64;
  float* Wt0   = w;  w += 8*64;
  float* Wt    = w;  w += 3*128*64;
  float* fwt   = w;  w += 3*128*64;

  hipLaunchKernelGGL(prep_w0_kernel, dim3(1),   dim3(384), 0, stream, cw0, Wt0);
  hipLaunchKernelGGL(prep_wc_kernel, dim3(96),  dim3(256), 0, stream, cws, Wt);
  hipLaunchKernelGGL(prep_fw_kernel, dim3(96),  dim3(256), 0, stream, fws, fwt);
  hipLaunchKernelGGL(prep_x_kernel,  dim3(ROWS/256), dim3(256), 0, stream, x, xt, xnorm);

  const size_t chunk = (size_t)NB*64*NPTS;

  // layer 0
  hipLaunchKernelGGL(knn0_kernel,  dim3(ROWS/4), dim3(256), 0, stream, xt, xnorm, idx);
  hipLaunchKernelGGL(conv0_kernel, dim3(ROWS/4), dim3(256), 0, stream,
                     idx, xt, Wt0, gam, bet, rmn, rvr, out, hpm);

  for (int i = 0; i < 3; ++i) {
    hipLaunchKernelGGL(fuse_kernel, dim3(ROWS/32), dim3(256), 0, stream,
                       hpm, reps + (size_t)i*NB*64*NPTS, fwt + (size_t)i*8192, hf, hnorm);
    hipLaunchKernelGGL(knn64_scan_kernel,  dim3((ROWS/256)*NSPLIT), dim3(256), 0, stream,
                       hf, hnorm, cand);
    hipLaunchKernelGGL(knn64_merge_kernel, dim3(ROWS/4), dim3(256), 0, stream, cand, idx);
    hipLaunchKernelGGL(convL_kernel, dim3(ROWS), dim3(256), 0, stream,
                       idx, hf, Wt + (size_t)i*8192, gam, bet, rmn, rvr, i + 1,
                       out + (size_t)(i+1)*chunk, hpm);
  }
}

// Round 7
// 3571.082 us; speedup vs baseline: 3.3706x; 1.2008x over previous
//
#include <hip/hip_runtime.h>
#include <math.h>

#define NPTS 8192
#define NB 2
#define KNN 20
#define ROWS (NB*NPTS)    // 16384
#define NSPLIT 16         // candidate-range splits per row (knn64)
#define CPS (NPTS/NSPLIT) // 512 candidates per scanner
#define KEEP 16           // approx top-KEEP per (row,split); P(overflow into NC=32) ~1e-6
#define NC 32             // survivors refined with exact np keys
#define TILE 32           // candidates staged per LDS tile

// Reference-replication rules (np/XLA fp32), used ONLY in knn0 + select refine:
//   inner[n,m] = sequential-c FMA chain (first term = rounded mul)
//   sq[n]      = sequential-c adds of ROUNDED squares (no FMA)
//   key        = (2.0f*inner - sq_n) - sq_m, all fp32
//   top-20     = stable (value desc, index asc)

__device__ __forceinline__ unsigned long long shfl_xor_u64(unsigned long long v, int m) {
  unsigned lo = (unsigned)__shfl_xor((int)(unsigned)(v & 0xFFFFFFFFull), m, 64);
  unsigned hi = (unsigned)__shfl_xor((int)(unsigned)(v >> 32), m, 64);
  return ((unsigned long long)hi << 32) | (unsigned long long)lo;
}

// map neg_d (fp32) to u64 so ascending u64 == (neg_d descending, idx ascending)
__device__ __forceinline__ unsigned long long packkey(float negd, int m) {
  unsigned nb = __float_as_uint(negd) ^ 0x80000000u;            // exact negation
  nb = (nb & 0x80000000u) ? ~nb : (nb | 0x80000000u);           // monotone asc map
  return ((unsigned long long)nb << 32) | (unsigned)m;
}

// u32 sortable: ascending u32 == negd descending (ties later resolved by idx)
__device__ __forceinline__ unsigned sortdesc32(float negd) {
  unsigned s = __float_as_uint(negd);
  s = (s & 0x80000000u) ? (s ^ 0xFFFFFFFFu) : (s | 0x80000000u); // asc in negd
  return ~s;                                                      // desc in negd
}

// ---------------- prep ----------------

__global__ void prep_w0_kernel(const float* __restrict__ cw0, float* __restrict__ Wt0) {
  const int tid = threadIdx.x;                 // 384 threads
  const int c = tid >> 6, o = tid & 63;
  if (tid < 384) Wt0[c*64 + o] = cw0[o*6 + c];
}

__global__ void prep_wc_kernel(const float* __restrict__ cws, float* __restrict__ Wt) {
  const int f = blockIdx.x*256 + threadIdx.x;  // < 3*8192
  const int i = f >> 13, r = f & 8191, c = r >> 6, o = r & 63;
  Wt[f] = cws[i*8192 + o*128 + c];
}

__global__ void prep_fw_kernel(const float* __restrict__ fws, float* __restrict__ fwt) {
  const int f = blockIdx.x*256 + threadIdx.x;  // < 3*8192
  const int i = f >> 13, r = f & 8191, c = r >> 6, o = r & 63;
  fwt[f] = fws[i*8192 + o*128 + c];
}

__global__ void prep_x_kernel(const float* __restrict__ x,
                              float* __restrict__ xt, float* __restrict__ xnorm) {
#pragma clang fp contract(off)
  const int t = blockIdx.x*256 + threadIdx.x;  // < ROWS
  const int b = t >> 13, n = t & (NPTS-1);
  const float v0 = x[((size_t)b*3 + 0)*NPTS + n];
  const float v1 = x[((size_t)b*3 + 1)*NPTS + n];
  const float v2 = x[((size_t)b*3 + 2)*NPTS + n];
  ((float4*)xt)[t] = make_float4(v0, v1, v2, 0.f);
  float a = __fmul_rn(v0, v0);
  a = __fadd_rn(a, __fmul_rn(v1, v1));
  a = __fadd_rn(a, __fmul_rn(v2, v2));
  xnorm[t] = a;
}

// ---------------- KNN layer 0 (wave-per-row; np-exact keys directly) ----------------
__global__ __launch_bounds__(256)
void knn0_kernel(const float* __restrict__ pts, const float* __restrict__ norms,
                 int* __restrict__ idx) {
#pragma clang fp contract(off)
  const int tid = threadIdx.x;
  const int wave = tid >> 6, lane = tid & 63;
  const int row = blockIdx.x*4 + wave;
  const int b = row >> 13, n = row & (NPTS-1);
  const float4* P = ((const float4*)pts) + (size_t)b * NPTS;
  const float4 rv = P[n];
  const float* nrm = norms + (size_t)b*NPTS;
  const float nrmN = nrm[n];

  unsigned long long keys[12];
#pragma unroll
  for (int i = 0; i < 12; ++i) keys[i] = ~0ull;

  for (int t = 0; t < NPTS/64; ++t) {
    const int m = t*64 + lane;
    const float4 q = P[m];
    float acc = __fmul_rn(rv.x, q.x);      // fma(a0,b0,0) == rounded mul
    acc = fmaf(rv.y, q.y, acc);
    acc = fmaf(rv.z, q.z, acc);
    const float negd = __fsub_rn(__fsub_rn(__fmul_rn(2.0f, acc), nrmN), nrm[m]);
    unsigned long long uk = packkey(negd, m);
    if (uk < keys[11]) {
#pragma unroll
      for (int i = 0; i < 12; ++i)
        if (uk < keys[i]) { const unsigned long long tmp = keys[i]; keys[i] = uk; uk = tmp; }
    }
  }

  int stash = 0;
  unsigned long long head = keys[0];
  for (int r = 0; r < KNN; ++r) {
    unsigned long long best = head;
#pragma unroll
    for (int off = 32; off; off >>= 1) {
      const unsigned long long o = shfl_xor_u64(best, off);
      if (o < best) best = o;
    }
    if (head == best) {
#pragma unroll
      for (int i = 0; i < 11; ++i) keys[i] = keys[i+1];
      keys[11] = ~0ull;
      head = keys[0];
    }
    if (lane == r) stash = (int)(unsigned)(best & 0xFFFFFFFFull);
  }
  if (lane < KNN) idx[(size_t)row*KNN + lane] = stash;
}

// ---------------- KNN 1-3 pass 1: approx scan (LDS-staged, thread-per-row) ----------------
// Approx keys (tree fp32) are a PREFILTER only; exact np ranking happens in select.
__global__ __launch_bounds__(256, 3)
void knn64_scan_kernel(const float* __restrict__ hf, const float* __restrict__ norms,
                       unsigned long long* __restrict__ cand) {
  __shared__ float4 tq[TILE*16];   // 32 cands x 64 ch = 8 KB
  __shared__ float tnrm[TILE];
  const int tid = threadIdx.x;
  const int rb = blockIdx.x >> 4, cs = blockIdx.x & (NSPLIT-1);
  const int row = rb*256 + tid;          // 256 consecutive rows; same batch
  const int b = row >> 13;
  const int csBase = cs*CPS;

  float4 f[16];
  const float4* Pf = ((const float4*)hf) + (size_t)row*16;
#pragma unroll
  for (int i = 0; i < 16; ++i) f[i] = Pf[i];
  const float nrmN = norms[row];
  const float* nrmC = norms + (size_t)b*NPTS + csBase;
  const float4* Pc4 = ((const float4*)hf) + ((size_t)b*NPTS + csBase)*16;

  unsigned keys[KEEP], idxs[KEEP];
#pragma unroll
  for (int i = 0; i < KEEP; ++i) { keys[i] = 0xFFFFFFFFu; idxs[i] = 0xFFFFFFFFu; }

  for (int t = 0; t < CPS/TILE; ++t) {
    tq[tid]       = Pc4[(size_t)t*512 + tid];
    tq[tid + 256] = Pc4[(size_t)t*512 + tid + 256];
    if (tid < TILE) tnrm[tid] = nrmC[t*TILE + tid];
    __syncthreads();
#pragma unroll 2
    for (int jj = 0; jj < TILE; ++jj) {
      const float4* q = &tq[jj*16];
      float a0 = 0.f, a1 = 0.f, a2 = 0.f, a3 = 0.f;
#pragma unroll
      for (int i = 0; i < 16; ++i) {
        const float4 q4 = q[i], f4 = f[i];
        a0 = fmaf(f4.x, q4.x, a0);
        a1 = fmaf(f4.y, q4.y, a1);
        a2 = fmaf(f4.z, q4.z, a2);
        a3 = fmaf(f4.w, q4.w, a3);
      }
      const float inner = (a0 + a1) + (a2 + a3);
      const float negd = 2.0f*inner - nrmN - tnrm[jj];
      const unsigned kd = sortdesc32(negd);
      if (kd < keys[KEEP-1]) {
        unsigned ck = kd, ci = (unsigned)(csBase + t*TILE + jj);
#pragma unroll
        for (int i = 0; i < KEEP; ++i) {
          const bool sh = (kd < keys[i]);   // vs ORIGINAL kd: ties keep idx-asc order
          const unsigned tk = keys[i], ti = idxs[i];
          keys[i] = sh ? ck : tk;  idxs[i] = sh ? ci : ti;
          ck      = sh ? tk : ck;  ci      = sh ? ti : ci;
        }
      }
    }
    __syncthreads();
  }

  unsigned long long* o = cand + ((size_t)row*NSPLIT + cs)*KEEP;
#pragma unroll
  for (int i = 0; i < KEEP; ++i)
    o[i] = ((unsigned long long)keys[i] << 32) | idxs[i];   // ascending (sorted)
}

// ---------------- KNN 1-3 pass 2: merge 256 -> top-32 approx -> np-exact top-20 ----------------
__global__ __launch_bounds__(256)
void knn64_select_kernel(const float* __restrict__ hf, const float* __restrict__ norms,
                         const unsigned long long* __restrict__ cand,
                         int* __restrict__ idx) {
#pragma clang fp contract(off)
  const int tid = threadIdx.x, wave = tid >> 6, lane = tid & 63;
  const int row = blockIdx.x*4 + wave;
  const int b = row >> 13;
  const unsigned long long* cr = cand + (size_t)row*(NSPLIT*KEEP);
  // lane holds 4 keys of one split-quarter: 16%4==0 -> within-split ascending
  unsigned long long a0 = cr[lane*4 + 0];
  unsigned long long a1 = cr[lane*4 + 1];
  unsigned long long a2 = cr[lane*4 + 2];
  unsigned long long a3 = cr[lane*4 + 3];

  int cidx = 0;
  for (int r = 0; r < NC; ++r) {
    unsigned long long best = a0;
#pragma unroll
    for (int off = 32; off; off >>= 1) {
      const unsigned long long o = shfl_xor_u64(best, off);
      if (o < best) best = o;
    }
    if (a0 == best) { a0 = a1; a1 = a2; a2 = a3; a3 = ~0ull; }
    if (lane == r) cidx = (int)(unsigned)(best & 0xFFFFFFFFull);
  }

  // np-exact key for the NC survivors (lane r holds candidate r)
  unsigned long long uk = ~0ull;
  if (lane < NC) {
    const float4* Pr = ((const float4*)hf) + (size_t)row*16;           // uniform
    const float4* Pc = ((const float4*)hf) + ((size_t)b*NPTS + cidx)*16;
    float4 fr = Pr[0], qc = Pc[0];
    float acc = __fmul_rn(fr.x, qc.x);
    acc = fmaf(fr.y, qc.y, acc);
    acc = fmaf(fr.z, qc.z, acc);
    acc = fmaf(fr.w, qc.w, acc);
#pragma unroll
    for (int i = 1; i < 16; ++i) {
      fr = Pr[i]; qc = Pc[i];
      acc = fmaf(fr.x, qc.x, acc);
      acc = fmaf(fr.y, qc.y, acc);
      acc = fmaf(fr.z, qc.z, acc);
      acc = fmaf(fr.w, qc.w, acc);
    }
    const float negd = __fsub_rn(__fsub_rn(__fmul_rn(2.0f, acc), norms[row]),
                                 norms[(size_t)b*NPTS + cidx]);
    uk = packkey(negd, cidx);
  }

  int stash = 0;
  for (int r = 0; r < KNN; ++r) {
    unsigned long long best = uk;
#pragma unroll
    for (int off = 32; off; off >>= 1) {
      const unsigned long long o = shfl_xor_u64(best, off);
      if (o < best) best = o;
    }
    if (lane == r) stash = (int)(unsigned)(best & 0xFFFFFFFFull);
    if (uk == best) uk = ~0ull;   // unique keys: exactly one lane retires
  }
  if (lane < KNN) idx[(size_t)row*KNN + lane] = stash;
}

// ---------------- conv layer 0: literal per-neighbor conv, BN, lrelu, max ----------------
__global__ __launch_bounds__(256)
void conv0_kernel(const int* __restrict__ idx, const float* __restrict__ xt,
                  const float* __restrict__ Wt0, const float* __restrict__ gam,
                  const float* __restrict__ bet, const float* __restrict__ rmn,
                  const float* __restrict__ rvr,
                  float* __restrict__ outc, float* __restrict__ hpm) {
#pragma clang fp contract(off)
  const int tid = threadIdx.x, wave = tid >> 6, lane = tid & 63;
  const int row = blockIdx.x*4 + wave;
  const int b = row >> 13, n = row & (NPTS-1);
  const float4* P = ((const float4*)xt) + (size_t)b * NPTS;
  const float4 ctr = P[n];
  float wv[6];
#pragma unroll
  for (int c = 0; c < 6; ++c) wv[c] = Wt0[c*64 + lane];
  const float sc = __fdiv_rn(gam[lane], sqrtf(__fadd_rn(rvr[lane], 1e-5f)));
  const float mn = rmn[lane], bt = bet[lane];

  float mx = -3.0e38f;
  const int* ip = idx + (size_t)row*KNN;
  for (int k = 0; k < KNN; ++k) {
    const float4 q = P[ip[k]];
    float acc = __fmul_rn(wv[0], __fsub_rn(q.x, ctr.x));
    acc = __fadd_rn(acc, __fmul_rn(wv[1], __fsub_rn(q.y, ctr.y)));
    acc = __fadd_rn(acc, __fmul_rn(wv[2], __fsub_rn(q.z, ctr.z)));
    acc = __fadd_rn(acc, __fmul_rn(wv[3], ctr.x));
    acc = __fadd_rn(acc, __fmul_rn(wv[4], ctr.y));
    acc = __fadd_rn(acc, __fmul_rn(wv[5], ctr.z));
    float y = __fadd_rn(__fmul_rn(__fsub_rn(acc, mn), sc), bt);
    y = (y >= 0.f) ? y : __fmul_rn(0.2f, y);
    mx = fmaxf(mx, y);
  }
  outc[((size_t)(b*64 + lane))*NPTS + n] = mx;
  hpm[(size_t)row*64 + lane] = mx;
}

// ---------------- conv layers 1-3: literal per-neighbor conv (128-ch), BN, lrelu, max ----------------
__global__ __launch_bounds__(256)
void convL_kernel(const int* __restrict__ idx, const float* __restrict__ hf,
                  const float* __restrict__ WtL, const float* __restrict__ gam,
                  const float* __restrict__ bet, const float* __restrict__ rmn,
                  const float* __restrict__ rvr, const int L,
                  float* __restrict__ outc, float* __restrict__ hpm) {
#pragma clang fp contract(off)
  __shared__ float ls[21*64];          // row 0 = ctr, rows 1..20 = neighbors
  __shared__ float pmax[4*64];
  const int tid = threadIdx.x, wave = tid >> 6, lane = tid & 63;
  const int row = blockIdx.x;
  const int b = row >> 13, n = row & (NPTS-1);
  const int* ip = idx + (size_t)row*KNN;
#pragma unroll
  for (int j = 0; j < 6; ++j) {
    const int r = j*4 + wave;
    if (r < 21) {
      const int src = (r == 0) ? row : (b*NPTS + ip[r-1]);
      ls[r*64 + lane] = hf[(size_t)src*64 + lane];
    }
  }
  __syncthreads();

  float wv[128];
#pragma unroll
  for (int c = 0; c < 128; ++c) wv[c] = WtL[c*64 + lane];
  const float sc = __fdiv_rn(gam[L*64 + lane], sqrtf(__fadd_rn(rvr[L*64 + lane], 1e-5f)));
  const float mn = rmn[L*64 + lane], bt = bet[L*64 + lane];

  float mx = -3.0e38f;
  for (int j = 0; j < 5; ++j) {
    const int k = wave*5 + j;
    const float* nb = &ls[(1+k)*64];
    float acc = __fmul_rn(wv[0], __fsub_rn(nb[0], ls[0]));
#pragma unroll
    for (int c = 1; c < 64; ++c)
      acc = __fadd_rn(acc, __fmul_rn(wv[c], __fsub_rn(nb[c], ls[c])));
#pragma unroll
    for (int c = 64; c < 128; ++c)
      acc = __fadd_rn(acc, __fmul_rn(wv[c], ls[c-64]));
    float y = __fadd_rn(__fmul_rn(__fsub_rn(acc, mn), sc), bt);
    y = (y >= 0.f) ? y : __fmul_rn(0.2f, y);
    mx = fmaxf(mx, y);
  }
  pmax[wave*64 + lane] = mx;
  __syncthreads();
  if (tid < 64) {
    const float m01 = fmaxf(pmax[tid], pmax[64 + tid]);
    const float m23 = fmaxf(pmax[128 + tid], pmax[192 + tid]);
    const float m = fmaxf(m01, m23);
    outc[((size_t)(b*64 + tid))*NPTS + n] = m;
    hpm[(size_t)row*64 + tid] = m;
  }
}

// ---------------- fuse: hf = elu(fw . [h; reps]); + hnorm (seq sum of rounded squares) ----------------
__global__ __launch_bounds__(256)
void fuse_kernel(const float* __restrict__ hpm, const float* __restrict__ repsL,
                 const float* __restrict__ fwtL, float* __restrict__ hf,
                 float* __restrict__ hnorm) {
#pragma clang fp contract(off)
  __shared__ float cs[32*130];   // 32 points x 128 channels (+2 pad)
  __shared__ float yb[32*65];    // fused outputs for the sq pass
  const int tid = threadIdx.x, wave = tid >> 6, lane = tid & 63;
  const size_t rowbase = (size_t)blockIdx.x*32;          // b*N + n0
  const int b = (int)(rowbase >> 13);
  const int n0 = (int)(rowbase & (NPTS-1));
#pragma unroll
  for (int j = 0; j < 8; ++j) {
    const int p = j*4 + wave;
    cs[p*130 + lane] = hpm[(rowbase + p)*64 + lane];
  }
  const float* rb = repsL + (size_t)b*64*NPTS;
  const int pl = lane & 31;
#pragma unroll
  for (int j = 0; j < 8; ++j) {
    const int c = j*8 + wave*2 + (lane >> 5);
    cs[pl*130 + 64 + c] = rb[(size_t)c*NPTS + n0 + pl];
  }
  __syncthreads();
  float wv[128];
#pragma unroll
  for (int c = 0; c < 128; ++c) wv[c] = fwtL[c*64 + lane];
  for (int pp = 0; pp < 8; ++pp) {
    const int p = wave*8 + pp;
    float acc = __fmul_rn(wv[0], cs[p*130]);
#pragma unroll
    for (int c = 1; c < 128; ++c)
      acc = __fadd_rn(acc, __fmul_rn(wv[c], cs[p*130 + c]));
    const float y = (acc > 0.f) ? acc : (float)expm1((double)acc);  // jax.nn.elu
    hf[(rowbase + p)*64 + lane] = y;
    yb[p*65 + lane] = y;
  }
  __syncthreads();
  if (tid < 32) {
    float a = __fmul_rn(yb[tid*65], yb[tid*65]);
#pragma unroll
    for (int c = 1; c < 64; ++c) {
      const float t = yb[tid*65 + c];
      a = __fadd_rn(a, __fmul_rn(t, t));
    }
    hnorm[rowbase + tid] = a;
  }
}

// ---------------- launch ----------------
extern "C" void kernel_launch(void* const* d_in, const int* in_sizes, int n_in,
                              void* d_out, int out_size, void* d_ws, size_t ws_size,
                              hipStream_t stream) {
  const float* x    = (const float*)d_in[0];
  const float* reps = (const float*)d_in[1];
  const float* cw0  = (const float*)d_in[2];
  const float* cws  = (const float*)d_in[3];
  const float* gam  = (const float*)d_in[4];
  const float* bet  = (const float*)d_in[5];
  const float* rmn  = (const float*)d_in[6];
  const float* rvr  = (const float*)d_in[7];
  const float* fws  = (const float*)d_in[8];
  float* out = (float*)d_out;

  unsigned long long* cand = (unsigned long long*)d_ws;  // ROWS*16*16 u64 = 33.6MB
  int* idx = (int*)(cand + (size_t)ROWS*NSPLIT*KEEP);
  float* w = (float*)(idx + (size_t)ROWS*KNN);
  float* xt    = w;  w += (size_t)ROWS*4;
  float* xnorm = w;  w += ROWS;
  float* hf    = w;  w += (size_t)ROWS*64;
  float* hnorm = w;  w += ROWS;
  float* hpm   = w;  w += (size_t)ROWS*64;
  float* Wt0   = w;  w += 8*64;
  float* Wt    = w;  w += 3*128*64;
  float* fwt   = w;  w += 3*128*64;

  hipLaunchKernelGGL(prep_w0_kernel, dim3(1),   dim3(384), 0, stream, cw0, Wt0);
  hipLaunchKernelGGL(prep_wc_kernel, dim3(96),  dim3(256), 0, stream, cws, Wt);
  hipLaunchKernelGGL(prep_fw_kernel, dim3(96),  dim3(256), 0, stream, fws, fwt);
  hipLaunchKernelGGL(prep_x_kernel,  dim3(ROWS/256), dim3(256), 0, stream, x, xt, xnorm);

  const size_t chunk = (size_t)NB*64*NPTS;

  // layer 0
  hipLaunchKernelGGL(knn0_kernel,  dim3(ROWS/4), dim3(256), 0, stream, xt, xnorm, idx);
  hipLaunchKernelGGL(conv0_kernel, dim3(ROWS/4), dim3(256), 0, stream,
                     idx, xt, Wt0, gam, bet, rmn, rvr, out, hpm);

  for (int i = 0; i < 3; ++i) {
    hipLaunchKernelGGL(fuse_kernel, dim3(ROWS/32), dim3(256), 0, stream,
                       hpm, reps + (size_t)i*NB*64*NPTS, fwt + (size_t)i*8192, hf, hnorm);
    hipLaunchKernelGGL(knn64_scan_kernel,  dim3((ROWS/256)*NSPLIT), dim3(256), 0, stream,
                       hf, hnorm, cand);
    hipLaunchKernelGGL(knn64_select_kernel, dim3(ROWS/4), dim3(256), 0, stream,
                       hf, hnorm, cand, idx);
    hipLaunchKernelGGL(convL_kernel, dim3(ROWS), dim3(256), 0, stream,
                       idx, hf, Wt + (size_t)i*8192, gam, bet, rmn, rvr, i + 1,
                       out + (size_t)(i+1)*chunk, hpm);
  }
}

// Round 8
// 3421.203 us; speedup vs baseline: 3.5182x; 1.0438x over previous
//
#include <hip/hip_runtime.h>
#include <math.h>

#define NPTS 8192
#define NB 2
#define KNN 20
#define ROWS (NB*NPTS)    // 16384
#define NSPLIT 16         // candidate-range splits per row (knn64)
#define CPS (NPTS/NSPLIT) // 512 candidates per scanner
#define KEEP 16           // approx top-KEEP per (row,split); P(overflow into NC=32) ~1e-6
#define NC 32             // survivors refined with exact np keys
#define TILE 64           // candidates staged per LDS tile

// Reference-replication rules (np/XLA fp32), used ONLY in knn0 + select refine:
//   inner[n,m] = sequential-c FMA chain (first term = rounded mul)
//   sq[n]      = sequential-c adds of ROUNDED squares (no FMA)
//   key        = (2.0f*inner - sq_n) - sq_m, all fp32
//   top-20     = stable (value desc, index asc)

__device__ __forceinline__ unsigned long long shfl_xor_u64(unsigned long long v, int m) {
  unsigned lo = (unsigned)__shfl_xor((int)(unsigned)(v & 0xFFFFFFFFull), m, 64);
  unsigned hi = (unsigned)__shfl_xor((int)(unsigned)(v >> 32), m, 64);
  return ((unsigned long long)hi << 32) | (unsigned long long)lo;
}

// map neg_d (fp32) to u64 so ascending u64 == (neg_d descending, idx ascending)
__device__ __forceinline__ unsigned long long packkey(float negd, int m) {
  unsigned nb = __float_as_uint(negd) ^ 0x80000000u;            // exact negation
  nb = (nb & 0x80000000u) ? ~nb : (nb | 0x80000000u);           // monotone asc map
  return ((unsigned long long)nb << 32) | (unsigned)m;
}

// u32 sortable: ascending u32 == negd descending (ties later resolved by idx)
__device__ __forceinline__ unsigned sortdesc32(float negd) {
  unsigned s = __float_as_uint(negd);
  s = (s & 0x80000000u) ? (s ^ 0xFFFFFFFFu) : (s | 0x80000000u); // asc in negd
  return ~s;                                                      // desc in negd
}

// ---------------- prep ----------------

__global__ void prep_w0_kernel(const float* __restrict__ cw0, float* __restrict__ Wt0) {
  const int tid = threadIdx.x;                 // 384 threads
  const int c = tid >> 6, o = tid & 63;
  if (tid < 384) Wt0[c*64 + o] = cw0[o*6 + c];
}

__global__ void prep_wc_kernel(const float* __restrict__ cws, float* __restrict__ Wt) {
  const int f = blockIdx.x*256 + threadIdx.x;  // < 3*8192
  const int i = f >> 13, r = f & 8191, c = r >> 6, o = r & 63;
  Wt[f] = cws[i*8192 + o*128 + c];
}

__global__ void prep_fw_kernel(const float* __restrict__ fws, float* __restrict__ fwt) {
  const int f = blockIdx.x*256 + threadIdx.x;  // < 3*8192
  const int i = f >> 13, r = f & 8191, c = r >> 6, o = r & 63;
  fwt[f] = fws[i*8192 + o*128 + c];
}

__global__ void prep_x_kernel(const float* __restrict__ x,
                              float* __restrict__ xt, float* __restrict__ xnorm) {
#pragma clang fp contract(off)
  const int t = blockIdx.x*256 + threadIdx.x;  // < ROWS
  const int b = t >> 13, n = t & (NPTS-1);
  const float v0 = x[((size_t)b*3 + 0)*NPTS + n];
  const float v1 = x[((size_t)b*3 + 1)*NPTS + n];
  const float v2 = x[((size_t)b*3 + 2)*NPTS + n];
  ((float4*)xt)[t] = make_float4(v0, v1, v2, 0.f);
  float a = __fmul_rn(v0, v0);
  a = __fadd_rn(a, __fmul_rn(v1, v1));
  a = __fadd_rn(a, __fmul_rn(v2, v2));
  xnorm[t] = a;
}

// ---------------- KNN layer 0 (wave-per-row; np-exact keys directly) ----------------
__global__ __launch_bounds__(256)
void knn0_kernel(const float* __restrict__ pts, const float* __restrict__ norms,
                 int* __restrict__ idx) {
#pragma clang fp contract(off)
  const int tid = threadIdx.x;
  const int wave = tid >> 6, lane = tid & 63;
  const int row = blockIdx.x*4 + wave;
  const int b = row >> 13, n = row & (NPTS-1);
  const float4* P = ((const float4*)pts) + (size_t)b * NPTS;
  const float4 rv = P[n];
  const float* nrm = norms + (size_t)b*NPTS;
  const float nrmN = nrm[n];

  unsigned long long keys[12];
#pragma unroll
  for (int i = 0; i < 12; ++i) keys[i] = ~0ull;

  for (int t = 0; t < NPTS/64; ++t) {
    const int m = t*64 + lane;
    const float4 q = P[m];
    float acc = __fmul_rn(rv.x, q.x);      // fma(a0,b0,0) == rounded mul
    acc = fmaf(rv.y, q.y, acc);
    acc = fmaf(rv.z, q.z, acc);
    const float negd = __fsub_rn(__fsub_rn(__fmul_rn(2.0f, acc), nrmN), nrm[m]);
    unsigned long long uk = packkey(negd, m);
    if (uk < keys[11]) {
#pragma unroll
      for (int i = 0; i < 12; ++i)
        if (uk < keys[i]) { const unsigned long long tmp = keys[i]; keys[i] = uk; uk = tmp; }
    }
  }

  int stash = 0;
  unsigned long long head = keys[0];
  for (int r = 0; r < KNN; ++r) {
    unsigned long long best = head;
#pragma unroll
    for (int off = 32; off; off >>= 1) {
      const unsigned long long o = shfl_xor_u64(best, off);
      if (o < best) best = o;
    }
    if (head == best) {
#pragma unroll
      for (int i = 0; i < 11; ++i) keys[i] = keys[i+1];
      keys[11] = ~0ull;
      head = keys[0];
    }
    if (lane == r) stash = (int)(unsigned)(best & 0xFFFFFFFFull);
  }
  if (lane < KNN) idx[(size_t)row*KNN + lane] = stash;
}

// ---------------- KNN 1-3 pass 1: approx scan (LDS-staged, thread-per-row) ----------------
// Approx keys (tree fp32) are a PREFILTER only; exact np ranking happens in select.
// Grid = 1024 blocks; launch_bounds(256,4) -> 4 blocks/CU -> whole grid
// co-resident in one round (no low-occupancy tail).
__global__ __launch_bounds__(256, 4)
void knn64_scan_kernel(const float* __restrict__ hf, const float* __restrict__ norms,
                       unsigned long long* __restrict__ cand) {
  __shared__ float4 tq[TILE*16];   // 64 cands x 64 ch = 16 KB
  __shared__ float tnrm[TILE];
  const int tid = threadIdx.x;
  const int rb = blockIdx.x >> 4, cs = blockIdx.x & (NSPLIT-1);
  const int row = rb*256 + tid;          // 256 consecutive rows; same batch
  const int b = row >> 13;
  const int csBase = cs*CPS;

  float4 f[16];
  const float4* Pf = ((const float4*)hf) + (size_t)row*16;
#pragma unroll
  for (int i = 0; i < 16; ++i) f[i] = Pf[i];
  const float nrmN = norms[row];
  const float* nrmC = norms + (size_t)b*NPTS + csBase;
  const float4* Pc4 = ((const float4*)hf) + ((size_t)b*NPTS + csBase)*16;

  unsigned keys[KEEP], idxs[KEEP];
#pragma unroll
  for (int i = 0; i < KEEP; ++i) { keys[i] = 0xFFFFFFFFu; idxs[i] = 0xFFFFFFFFu; }

  for (int t = 0; t < CPS/TILE; ++t) {
#pragma unroll
    for (int j = 0; j < (TILE*16)/256; ++j)
      tq[tid + j*256] = Pc4[(size_t)t*(TILE*16) + tid + j*256];
    if (tid < TILE) tnrm[tid] = nrmC[t*TILE + tid];
    __syncthreads();
#pragma unroll 2
    for (int jj = 0; jj < TILE; ++jj) {
      const float4* q = &tq[jj*16];
      float a0 = 0.f, a1 = 0.f, a2 = 0.f, a3 = 0.f;
#pragma unroll
      for (int i = 0; i < 16; ++i) {
        const float4 q4 = q[i], f4 = f[i];
        a0 = fmaf(f4.x, q4.x, a0);
        a1 = fmaf(f4.y, q4.y, a1);
        a2 = fmaf(f4.z, q4.z, a2);
        a3 = fmaf(f4.w, q4.w, a3);
      }
      const float inner = (a0 + a1) + (a2 + a3);
      const float negd = 2.0f*inner - nrmN - tnrm[jj];
      const unsigned kd = sortdesc32(negd);
      if (kd < keys[KEEP-1]) {
        unsigned ck = kd, ci = (unsigned)(csBase + t*TILE + jj);
#pragma unroll
        for (int i = 0; i < KEEP; ++i) {
          const bool sh = (kd < keys[i]);   // vs ORIGINAL kd: ties keep idx-asc order
          const unsigned tk = keys[i], ti = idxs[i];
          keys[i] = sh ? ck : tk;  idxs[i] = sh ? ci : ti;
          ck      = sh ? tk : ck;  ci      = sh ? ti : ci;
        }
      }
    }
    __syncthreads();
  }

  unsigned long long* o = cand + ((size_t)row*NSPLIT + cs)*KEEP;
#pragma unroll
  for (int i = 0; i < KEEP; ++i)
    o[i] = ((unsigned long long)keys[i] << 32) | idxs[i];   // ascending (sorted)
}

// ---------------- KNN 1-3 pass 2: merge 256 -> top-32 approx -> np-exact top-20 ----------------
__global__ __launch_bounds__(256)
void knn64_select_kernel(const float* __restrict__ hf, const float* __restrict__ norms,
                         const unsigned long long* __restrict__ cand,
                         int* __restrict__ idx) {
#pragma clang fp contract(off)
  const int tid = threadIdx.x, wave = tid >> 6, lane = tid & 63;
  const int row = blockIdx.x*4 + wave;
  const int b = row >> 13;
  const unsigned long long* cr = cand + (size_t)row*(NSPLIT*KEEP);
  // lane holds 4 keys of one split-quarter: 16%4==0 -> within-split ascending
  unsigned long long a0 = cr[lane*4 + 0];
  unsigned long long a1 = cr[lane*4 + 1];
  unsigned long long a2 = cr[lane*4 + 2];
  unsigned long long a3 = cr[lane*4 + 3];

  int cidx = 0;
  for (int r = 0; r < NC; ++r) {
    unsigned long long best = a0;
#pragma unroll
    for (int off = 32; off; off >>= 1) {
      const unsigned long long o = shfl_xor_u64(best, off);
      if (o < best) best = o;
    }
    if (a0 == best) { a0 = a1; a1 = a2; a2 = a3; a3 = ~0ull; }
    if (lane == r) cidx = (int)(unsigned)(best & 0xFFFFFFFFull);
  }

  // np-exact key for the NC survivors (lane r holds candidate r)
  unsigned long long uk = ~0ull;
  if (lane < NC) {
    const float4* Pr = ((const float4*)hf) + (size_t)row*16;           // uniform
    const float4* Pc = ((const float4*)hf) + ((size_t)b*NPTS + cidx)*16;
    float4 fr = Pr[0], qc = Pc[0];
    float acc = __fmul_rn(fr.x, qc.x);
    acc = fmaf(fr.y, qc.y, acc);
    acc = fmaf(fr.z, qc.z, acc);
    acc = fmaf(fr.w, qc.w, acc);
#pragma unroll
    for (int i = 1; i < 16; ++i) {
      fr = Pr[i]; qc = Pc[i];
      acc = fmaf(fr.x, qc.x, acc);
      acc = fmaf(fr.y, qc.y, acc);
      acc = fmaf(fr.z, qc.z, acc);
      acc = fmaf(fr.w, qc.w, acc);
    }
    const float negd = __fsub_rn(__fsub_rn(__fmul_rn(2.0f, acc), norms[row]),
                                 norms[(size_t)b*NPTS + cidx]);
    uk = packkey(negd, cidx);
  }

  int stash = 0;
  for (int r = 0; r < KNN; ++r) {
    unsigned long long best = uk;
#pragma unroll
    for (int off = 32; off; off >>= 1) {
      const unsigned long long o = shfl_xor_u64(best, off);
      if (o < best) best = o;
    }
    if (lane == r) stash = (int)(unsigned)(best & 0xFFFFFFFFull);
    if (uk == best) uk = ~0ull;   // unique keys: exactly one lane retires
  }
  if (lane < KNN) idx[(size_t)row*KNN + lane] = stash;
}

// ---------------- conv layer 0: literal per-neighbor conv, BN, lrelu, max ----------------
__global__ __launch_bounds__(256)
void conv0_kernel(const int* __restrict__ idx, const float* __restrict__ xt,
                  const float* __restrict__ Wt0, const float* __restrict__ gam,
                  const float* __restrict__ bet, const float* __restrict__ rmn,
                  const float* __restrict__ rvr,
                  float* __restrict__ outc, float* __restrict__ hpm) {
#pragma clang fp contract(off)
  const int tid = threadIdx.x, wave = tid >> 6, lane = tid & 63;
  const int row = blockIdx.x*4 + wave;
  const int b = row >> 13, n = row & (NPTS-1);
  const float4* P = ((const float4*)xt) + (size_t)b * NPTS;
  const float4 ctr = P[n];
  float wv[6];
#pragma unroll
  for (int c = 0; c < 6; ++c) wv[c] = Wt0[c*64 + lane];
  const float sc = __fdiv_rn(gam[lane], sqrtf(__fadd_rn(rvr[lane], 1e-5f)));
  const float mn = rmn[lane], bt = bet[lane];

  float mx = -3.0e38f;
  const int* ip = idx + (size_t)row*KNN;
  for (int k = 0; k < KNN; ++k) {
    const float4 q = P[ip[k]];
    float acc = __fmul_rn(wv[0], __fsub_rn(q.x, ctr.x));
    acc = __fadd_rn(acc, __fmul_rn(wv[1], __fsub_rn(q.y, ctr.y)));
    acc = __fadd_rn(acc, __fmul_rn(wv[2], __fsub_rn(q.z, ctr.z)));
    acc = __fadd_rn(acc, __fmul_rn(wv[3], ctr.x));
    acc = __fadd_rn(acc, __fmul_rn(wv[4], ctr.y));
    acc = __fadd_rn(acc, __fmul_rn(wv[5], ctr.z));
    float y = __fadd_rn(__fmul_rn(__fsub_rn(acc, mn), sc), bt);
    y = (y >= 0.f) ? y : __fmul_rn(0.2f, y);
    mx = fmaxf(mx, y);
  }
  outc[((size_t)(b*64 + lane))*NPTS + n] = mx;
  hpm[(size_t)row*64 + lane] = mx;
}

// ---------------- conv layers 1-3: literal per-neighbor conv (128-ch), BN, lrelu, max ----------------
__global__ __launch_bounds__(256)
void convL_kernel(const int* __restrict__ idx, const float* __restrict__ hf,
                  const float* __restrict__ WtL, const float* __restrict__ gam,
                  const float* __restrict__ bet, const float* __restrict__ rmn,
                  const float* __restrict__ rvr, const int L,
                  float* __restrict__ outc, float* __restrict__ hpm) {
#pragma clang fp contract(off)
  __shared__ float ls[21*64];          // row 0 = ctr, rows 1..20 = neighbors
  __shared__ float pmax[4*64];
  const int tid = threadIdx.x, wave = tid >> 6, lane = tid & 63;
  const int row = blockIdx.x;
  const int b = row >> 13, n = row & (NPTS-1);
  const int* ip = idx + (size_t)row*KNN;
#pragma unroll
  for (int j = 0; j < 6; ++j) {
    const int r = j*4 + wave;
    if (r < 21) {
      const int src = (r == 0) ? row : (b*NPTS + ip[r-1]);
      ls[r*64 + lane] = hf[(size_t)src*64 + lane];
    }
  }
  __syncthreads();

  float wv[128];
#pragma unroll
  for (int c = 0; c < 128; ++c) wv[c] = WtL[c*64 + lane];
  const float sc = __fdiv_rn(gam[L*64 + lane], sqrtf(__fadd_rn(rvr[L*64 + lane], 1e-5f)));
  const float mn = rmn[L*64 + lane], bt = bet[L*64 + lane];

  float mx = -3.0e38f;
  for (int j = 0; j < 5; ++j) {
    const int k = wave*5 + j;
    const float* nb = &ls[(1+k)*64];
    float acc = __fmul_rn(wv[0], __fsub_rn(nb[0], ls[0]));
#pragma unroll
    for (int c = 1; c < 64; ++c)
      acc = __fadd_rn(acc, __fmul_rn(wv[c], __fsub_rn(nb[c], ls[c])));
#pragma unroll
    for (int c = 64; c < 128; ++c)
      acc = __fadd_rn(acc, __fmul_rn(wv[c], ls[c-64]));
    float y = __fadd_rn(__fmul_rn(__fsub_rn(acc, mn), sc), bt);
    y = (y >= 0.f) ? y : __fmul_rn(0.2f, y);
    mx = fmaxf(mx, y);
  }
  pmax[wave*64 + lane] = mx;
  __syncthreads();
  if (tid < 64) {
    const float m01 = fmaxf(pmax[tid], pmax[64 + tid]);
    const float m23 = fmaxf(pmax[128 + tid], pmax[192 + tid]);
    const float m = fmaxf(m01, m23);
    outc[((size_t)(b*64 + tid))*NPTS + n] = m;
    hpm[(size_t)row*64 + tid] = m;
  }
}

// ---------------- fuse: hf = elu(fw . [h; reps]); + hnorm (seq sum of rounded squares) ----------------
__global__ __launch_bounds__(256)
void fuse_kernel(const float* __restrict__ hpm, const float* __restrict__ repsL,
                 const float* __restrict__ fwtL, float* __restrict__ hf,
                 float* __restrict__ hnorm) {
#pragma clang fp contract(off)
  __shared__ float cs[32*130];   // 32 points x 128 channels (+2 pad)
  __shared__ float yb[32*65];    // fused outputs for the sq pass
  const int tid = threadIdx.x, wave = tid >> 6, lane = tid & 63;
  const size_t rowbase = (size_t)blockIdx.x*32;          // b*N + n0
  const int b = (int)(rowbase >> 13);
  const int n0 = (int)(rowbase & (NPTS-1));
#pragma unroll
  for (int j = 0; j < 8; ++j) {
    const int p = j*4 + wave;
    cs[p*130 + lane] = hpm[(rowbase + p)*64 + lane];
  }
  const float* rb = repsL + (size_t)b*64*NPTS;
  const int pl = lane & 31;
#pragma unroll
  for (int j = 0; j < 8; ++j) {
    const int c = j*8 + wave*2 + (lane >> 5);
    cs[pl*130 + 64 + c] = rb[(size_t)c*NPTS + n0 + pl];
  }
  __syncthreads();
  float wv[128];
#pragma unroll
  for (int c = 0; c < 128; ++c) wv[c] = fwtL[c*64 + lane];
  for (int pp = 0; pp < 8; ++pp) {
    const int p = wave*8 + pp;
    float acc = __fmul_rn(wv[0], cs[p*130]);
#pragma unroll
    for (int c = 1; c < 128; ++c)
      acc = __fadd_rn(acc, __fmul_rn(wv[c], cs[p*130 + c]));
    const float y = (acc > 0.f) ? acc : (float)expm1((double)acc);  // jax.nn.elu
    hf[(rowbase + p)*64 + lane] = y;
    yb[p*65 + lane] = y;
  }
  __syncthreads();
  if (tid < 32) {
    float a = __fmul_rn(yb[tid*65], yb[tid*65]);
#pragma unroll
    for (int c = 1; c < 64; ++c) {
      const float t = yb[tid*65 + c];
      a = __fadd_rn(a, __fmul_rn(t, t));
    }
    hnorm[rowbase + tid] = a;
  }
}

// ---------------- launch ----------------
extern "C" void kernel_launch(void* const* d_in, const int* in_sizes, int n_in,
                              void* d_out, int out_size, void* d_ws, size_t ws_size,
                              hipStream_t stream) {
  const float* x    = (const float*)d_in[0];
  const float* reps = (const float*)d_in[1];
  const float* cw0  = (const float*)d_in[2];
  const float* cws  = (const float*)d_in[3];
  const float* gam  = (const float*)d_in[4];
  const float* bet  = (const float*)d_in[5];
  const float* rmn  = (const float*)d_in[6];
  const float* rvr  = (const float*)d_in[7];
  const float* fws  = (const float*)d_in[8];
  float* out = (float*)d_out;

  unsigned long long* cand = (unsigned long long*)d_ws;  // ROWS*16*16 u64 = 33.6MB
  int* idx = (int*)(cand + (size_t)ROWS*NSPLIT*KEEP);
  float* w = (float*)(idx + (size_t)ROWS*KNN);
  float* xt    = w;  w += (size_t)ROWS*4;
  float* xnorm = w;  w += ROWS;
  float* hf    = w;  w += (size_t)ROWS*64;
  float* hnorm = w;  w += ROWS;
  float* hpm   = w;  w += (size_t)ROWS*64;
  float* Wt0   = w;  w += 8*64;
  float* Wt    = w;  w += 3*128*64;
  float* fwt   = w;  w += 3*128*64;

  hipLaunchKernelGGL(prep_w0_kernel, dim3(1),   dim3(384), 0, stream, cw0, Wt0);
  hipLaunchKernelGGL(prep_wc_kernel, dim3(96),  dim3(256), 0, stream, cws, Wt);
  hipLaunchKernelGGL(prep_fw_kernel, dim3(96),  dim3(256), 0, stream, fws, fwt);
  hipLaunchKernelGGL(prep_x_kernel,  dim3(ROWS/256), dim3(256), 0, stream, x, xt, xnorm);

  const size_t chunk = (size_t)NB*64*NPTS;

  // layer 0
  hipLaunchKernelGGL(knn0_kernel,  dim3(ROWS/4), dim3(256), 0, stream, xt, xnorm, idx);
  hipLaunchKernelGGL(conv0_kernel, dim3(ROWS/4), dim3(256), 0, stream,
                     idx, xt, Wt0, gam, bet, rmn, rvr, out, hpm);

  for (int i = 0; i < 3; ++i) {
    hipLaunchKernelGGL(fuse_kernel, dim3(ROWS/32), dim3(256), 0, stream,
                       hpm, reps + (size_t)i*NB*64*NPTS, fwt + (size_t)i*8192, hf, hnorm);
    hipLaunchKernelGGL(knn64_scan_kernel,  dim3((ROWS/256)*NSPLIT), dim3(256), 0, stream,
                       hf, hnorm, cand);
    hipLaunchKernelGGL(knn64_select_kernel, dim3(ROWS/4), dim3(256), 0, stream,
                       hf, hnorm, cand, idx);
    hipLaunchKernelGGL(convL_kernel, dim3(ROWS), dim3(256), 0, stream,
                       idx, hf, Wt + (size_t)i*8192, gam, bet, rmn, rvr, i + 1,
                       out + (size_t)(i+1)*chunk, hpm);
  }
}